// Round 7
// baseline (466.499 us; speedup 1.0000x reference)
//
#include <hip/hip_runtime.h>
#include <hip/hip_bf16.h>

#define N_ROWS 8192
#define DIM 512
#define C_CLSN 1000
#define C_PAD 1024
#define LOW_THRE (1.0f / 1000.0f)
#define LDK 40   // padded LDS leading dim (bf16 elems) to break bank conflicts

typedef __bf16 bf16x8 __attribute__((ext_vector_type(8)));
typedef float floatx4 __attribute__((ext_vector_type(4)));
typedef unsigned long long ull;
typedef ull ull2 __attribute__((ext_vector_type(2)));

// ---------------- KZ: detect conf_mask storage (int32 / uint8 / int64) -------
__global__ __launch_bounds__(256) void kz_detect_v7(const int* __restrict__ conf,
                                                    int* __restrict__ flag) {
  __shared__ int sbad, sodd1, seven1;
  int tid = threadIdx.x;
  if (tid == 0) { sbad = 0; sodd1 = 0; seven1 = 0; }
  __syncthreads();
  for (int i = tid; i < 2048; i += 256) {
    int v = conf[i];
    if (v != 0 && v != 1) atomicOr(&sbad, 1);
    if (v == 1) { if (i & 1) atomicAdd(&sodd1, 1); else atomicAdd(&seven1, 1); }
  }
  __syncthreads();
  if (tid == 0) {
    int mode = 0;                                // int32 0/1
    if (sbad) mode = 1;                          // packed uint8 bools
    else if (seven1 > 0 && sodd1 == 0) mode = 2; // int64 0/1
    flag[0] = mode;
  }
}

__device__ __forceinline__ bool read_conf(const int* conf, int mode, int r) {
  if (mode == 1) return ((const unsigned char*)conf)[r] != 0;
  if (mode == 2) return ((const long long*)conf)[r] != 0;
  return conf[r] != 0;
}

// ---------------- KP: stable partition rows by conf (conf first) -------------
__global__ __launch_bounds__(1024) void kp_perm_v7(const int* __restrict__ conf,
                                                   const int* __restrict__ cmode,
                                                   int* __restrict__ perm,
                                                   int* __restrict__ counters) {
  int tid = threadIdx.x;
  __shared__ int sc[1024];
  int mode = cmode[0];
  int r0 = tid * 8;
  int f[8]; int cnt = 0;
  #pragma unroll
  for (int k = 0; k < 8; ++k) { f[k] = read_conf(conf, mode, r0 + k) ? 1 : 0; cnt += f[k]; }
  sc[tid] = cnt;
  __syncthreads();
  for (int off = 1; off < 1024; off <<= 1) {
    int v = (tid >= off) ? sc[tid - off] : 0;
    __syncthreads();
    sc[tid] += v;
    __syncthreads();
  }
  int incl = sc[tid];
  int excl = incl - cnt;
  int total = sc[1023];
  if (tid == 0) counters[3] = total;
  int cpos = excl;
  int npos = total + (r0 - excl);
  #pragma unroll
  for (int k = 0; k < 8; ++k) {
    if (f[k]) perm[cpos++] = r0 + k;
    else      perm[npos++] = r0 + k;
  }
}

// ---------------- KA: L2-normalize feature rows -> bf16 (permuted order) -----
__global__ __launch_bounds__(64) void ka_featnorm_v7(const float* __restrict__ feature,
                                                     const int* __restrict__ perm,
                                                     __bf16* __restrict__ featBF) {
  int p = blockIdx.x;
  int orig = perm[p];
  int l = threadIdx.x;
  const float* fr = feature + (size_t)orig * DIM;
  int c0 = l * 8;
  float4 v0 = *(const float4*)(fr + c0);
  float4 v1 = *(const float4*)(fr + c0 + 4);
  float ss = v0.x*v0.x + v0.y*v0.y + v0.z*v0.z + v0.w*v0.w
           + v1.x*v1.x + v1.y*v1.y + v1.z*v1.z + v1.w*v1.w;
  #pragma unroll
  for (int m = 1; m < 64; m <<= 1) ss += __shfl_xor(ss, m);
  float sc = 1.0f / fmaxf(sqrtf(ss), 1e-12f);
  bf16x8 bv;
  bv[0] = (__bf16)(v0.x * sc); bv[1] = (__bf16)(v0.y * sc);
  bv[2] = (__bf16)(v0.z * sc); bv[3] = (__bf16)(v0.w * sc);
  bv[4] = (__bf16)(v1.x * sc); bv[5] = (__bf16)(v1.y * sc);
  bv[6] = (__bf16)(v1.z * sc); bv[7] = (__bf16)(v1.w * sc);
  *(bf16x8*)(featBF + (size_t)p * DIM + c0) = bv;
}

// ---------------- KB: proj[c][d] = sum_k raw[c][k] * cP[d][k] ----------------
__global__ __launch_bounds__(256) void kb_proj_v7(const float* __restrict__ raw,
                                                  const float* __restrict__ cP,
                                                  float* __restrict__ proj) {
  int tid = threadIdx.x;
  int c0 = blockIdx.x * 8;
  __shared__ float sraw[8 * DIM];  // 16 KB
  for (int idx = tid; idx < 8 * DIM; idx += 256)
    sraw[idx] = raw[(size_t)c0 * DIM + idx];
  __syncthreads();
  int d0 = tid, d1 = tid + 256;
  float acc0[8], acc1[8];
  #pragma unroll
  for (int cc = 0; cc < 8; ++cc) { acc0[cc] = 0.f; acc1[cc] = 0.f; }
  for (int k = 0; k < DIM; k += 4) {
    float4 w0 = *(const float4*)&cP[(size_t)d0 * DIM + k];
    float4 w1 = *(const float4*)&cP[(size_t)d1 * DIM + k];
    #pragma unroll
    for (int cc = 0; cc < 8; ++cc) {
      const float* sr = &sraw[cc * DIM + k];
      acc0[cc] += sr[0]*w0.x + sr[1]*w0.y + sr[2]*w0.z + sr[3]*w0.w;
      acc1[cc] += sr[0]*w1.x + sr[1]*w1.y + sr[2]*w1.z + sr[3]*w1.w;
    }
  }
  #pragma unroll
  for (int cc = 0; cc < 8; ++cc) {
    proj[(size_t)(c0 + cc) * DIM + d0] = acc0[cc];
    proj[(size_t)(c0 + cc) * DIM + d1] = acc1[cc];
  }
}

// ---------------- KC: normalize proxy -> bf16 (rows >= C_CLSN zeroed) --------
__global__ __launch_bounds__(64) void kc_norm_v7(const float* __restrict__ proj,
                                                 __bf16* __restrict__ proxyBF) {
  int r = blockIdx.x, l = threadIdx.x;
  int c0 = l * 8;
  if (r >= C_CLSN) {               // zero-pad rows 1000..1023 (MFMA-neutral)
    float4 z = {0.f, 0.f, 0.f, 0.f};
    *(float4*)(proxyBF + (size_t)r * DIM + c0) = z;   // 16 B of zero bf16
    return;
  }
  const float* pr = proj + (size_t)r * DIM;
  float4 v0 = *(const float4*)(pr + c0);
  float4 v1 = *(const float4*)(pr + c0 + 4);
  float ss = v0.x*v0.x + v0.y*v0.y + v0.z*v0.z + v0.w*v0.w
           + v1.x*v1.x + v1.y*v1.y + v1.z*v1.z + v1.w*v1.w;
  #pragma unroll
  for (int m = 1; m < 64; m <<= 1) ss += __shfl_xor(ss, m);
  float sc = 1.0f / fmaxf(sqrtf(ss), 1e-12f);
  bf16x8 bv;
  bv[0] = (__bf16)(v0.x * sc); bv[1] = (__bf16)(v0.y * sc);
  bv[2] = (__bf16)(v0.z * sc); bv[3] = (__bf16)(v0.w * sc);
  bv[4] = (__bf16)(v1.x * sc); bv[5] = (__bf16)(v1.y * sc);
  bv[6] = (__bf16)(v1.z * sc); bv[7] = (__bf16)(v1.w * sc);
  *(bf16x8*)(proxyBF + (size_t)r * DIM + c0) = bv;
}

// ---------------- KD: prob streaming — wave per row, ballot bitsets ----------
__global__ __launch_bounds__(256) void kd_prob_v7(const float* __restrict__ prob,
                                                  const int* __restrict__ perm,
                                                  ull* __restrict__ bits,
                                                  int* __restrict__ top1a,
                                                  int* counters) {
  int wv = threadIdx.x >> 6, lane = threadIdx.x & 63;
  int p = blockIdx.x * 4 + wv;
  int orig = perm[p];
  bool is_conf = p < counters[3];              // partitioned: conf rows first
  const float* pr = prob + (size_t)orig * C_CLSN;
  float bv = -1e30f; int bidx = 0x7fffffff;
  int cnt = 0;
  ull myword = 0ULL;
  #pragma unroll
  for (int pass = 0; pass < 16; ++pass) {
    int c = pass * 64 + lane;
    float pv = (c < C_CLSN) ? pr[c] : -1.0f;
    if (pv > bv) { bv = pv; bidx = c; }        // ascending: keeps first max
    ull m = __ballot((c < C_CLSN) && (pv > LOW_THRE));  // candidate word = ballot
    cnt += (int)__popcll(m);
    if (lane == pass) myword = m;
  }
  // wave argmax (first-occurrence tie-break: lower idx)
  #pragma unroll
  for (int m = 1; m < 64; m <<= 1) {
    float ov = __shfl_xor(bv, m); int oi = __shfl_xor(bidx, m);
    if (ov > bv || (ov == bv && oi < bidx)) { bv = ov; bidx = oi; }
  }
  int top1 = bidx;
  if (is_conf && lane < 16)                    // pred_class = one-hot(top1)
    myword = (lane == (top1 >> 6)) ? (1ULL << (top1 & 63)) : 0ULL;
  if (lane < 16) bits[(size_t)p * 16 + lane] = myword;
  if (lane == 0) {
    top1a[p] = top1;
    if (!is_conf) {
      atomicAdd(&counters[0], cnt);            // sc_count
      atomicAdd(&counters[1], 1);              // denom
    }
  }
}

// ---------------- KG: P = feat @ proxy^T, fused pos-pair epilogue ------------
// scsim[i] += sum_c (prob[i,c]>thre ? prob[i,c]*P[i,c] : 0); possim[i] = P[i,top1_i]
__global__ __launch_bounds__(256) void kg_pgemm_v7(const __bf16* __restrict__ featBF,
                                                   const __bf16* __restrict__ proxyBF,
                                                   const float* __restrict__ prob,
                                                   const int* __restrict__ perm,
                                                   const int* __restrict__ top1a,
                                                   float* __restrict__ scsim,
                                                   float* __restrict__ possim) {
  __shared__ __align__(16) __bf16 As[128 * LDK];
  __shared__ __align__(16) __bf16 Bs[128 * LDK];
  __shared__ int pO[128], t1r[128];

  int bi = blockIdx.x >> 3;     // 64 row-tiles
  int bj = blockIdx.x & 7;      // 8 class-tiles (C padded to 1024)

  int tid = threadIdx.x;
  int wv = tid >> 6, lane = tid & 63;
  int wi = wv >> 1, wj = wv & 1;
  int lr = lane >> 4, lc = lane & 15;

  if (tid < 128) { pO[tid] = perm[bi * 128 + tid]; t1r[tid] = top1a[bi * 128 + tid]; }

  floatx4 acc[4][4];
  floatx4 zero = {0.f, 0.f, 0.f, 0.f};
  #pragma unroll
  for (int ti = 0; ti < 4; ++ti)
    #pragma unroll
    for (int tj = 0; tj < 4; ++tj) acc[ti][tj] = zero;

  const __bf16* Abase = featBF + (size_t)bi * 128 * DIM;
  const __bf16* Bbase = proxyBF + (size_t)bj * 128 * DIM;

  for (int kt = 0; kt < DIM; kt += 32) {
    __syncthreads();
    #pragma unroll
    for (int t = 0; t < 2; ++t) {
      int idx = tid + t * 256;
      int rw = idx >> 2, cc = (idx & 3) * 8;
      *(bf16x8*)&As[rw * LDK + cc] = *(const bf16x8*)&Abase[(size_t)rw * DIM + kt + cc];
      *(bf16x8*)&Bs[rw * LDK + cc] = *(const bf16x8*)&Bbase[(size_t)rw * DIM + kt + cc];
    }
    __syncthreads();
    bf16x8 afr[4], bfr[4];
    #pragma unroll
    for (int ti = 0; ti < 4; ++ti)
      afr[ti] = *(bf16x8*)&As[(wi * 64 + ti * 16 + lc) * LDK + lr * 8];
    #pragma unroll
    for (int tj = 0; tj < 4; ++tj)
      bfr[tj] = *(bf16x8*)&Bs[(wj * 64 + tj * 16 + lc) * LDK + lr * 8];
    #pragma unroll
    for (int ti = 0; ti < 4; ++ti)
      #pragma unroll
      for (int tj = 0; tj < 4; ++tj)
        acc[ti][tj] = __builtin_amdgcn_mfma_f32_16x16x32_bf16(afr[ti], bfr[tj], acc[ti][tj], 0, 0, 0);
  }
  __syncthreads();

  #pragma unroll
  for (int ti = 0; ti < 4; ++ti) {
    int ibase = wi * 64 + ti * 16 + lr * 4;   // C/D: row=(lane>>4)*4+reg, col=lane&15
    float rs[4] = {0.f, 0.f, 0.f, 0.f};
    #pragma unroll
    for (int rr = 0; rr < 4; ++rr) {
      int il = ibase + rr;
      int orig = pO[il];
      int t1 = t1r[il];
      const float* prow = prob + (size_t)orig * C_CLSN;
      #pragma unroll
      for (int tj = 0; tj < 4; ++tj) {
        int c = bj * 128 + wj * 64 + tj * 16 + lc;
        float P = acc[ti][tj][rr];
        float pv = (c < C_CLSN) ? prow[c] : 0.f;
        if (pv > LOW_THRE) rs[rr] += pv * P;
        if (c == t1) possim[bi * 128 + il] = P;   // single writer grid-wide
      }
    }
    #pragma unroll
    for (int m = 1; m < 16; m <<= 1)
      #pragma unroll
      for (int rr = 0; rr < 4; ++rr) rs[rr] += __shfl_xor(rs[rr], m);
    if (lc == 0) {
      #pragma unroll
      for (int rr = 0; rr < 4; ++rr)
        atomicAdd(&scsim[bi * 128 + ibase + rr], rs[rr]);
    }
  }
}

// ---------------- KE: fused sim GEMM + tile-specialized mask + sum(exp) ------
// Upper-triangular tiles + mirror. UNCHANGED from v6 (195 us, verified).
__global__ __launch_bounds__(256) void ke_sim_v7(const __bf16* __restrict__ featBF,
                                                 const ull* __restrict__ bits,
                                                 const int* __restrict__ top1a,
                                                 const int* __restrict__ counters_ro,
                                                 float* __restrict__ S) {
  __shared__ __align__(16) __bf16 As[128 * LDK];
  __shared__ __align__(16) __bf16 Bs[128 * LDK];
  __shared__ ull bsI[16 * 128];
  __shared__ ull bsJ[16 * 128];
  __shared__ int t1I[128], t1J[128];

  int b = blockIdx.x;
  int bi = 0, rem = b;
  while (rem >= 64 - bi) { rem -= 64 - bi; bi++; }
  int bj = bi + rem;

  int nconf = counters_ro[3];
  bool allcI = (bi * 128 + 128) <= nconf;
  bool allcJ = (bj * 128 + 128) <= nconf;
  int mode = allcJ ? 0 : (allcI ? 1 : 3);

  int tid = threadIdx.x;
  int wv = tid >> 6, lane = tid & 63;
  int wi = wv >> 1, wj = wv & 1;
  int lr = lane >> 4, lc = lane & 15;

  if (tid < 128)      t1I[tid]       = top1a[bi * 128 + tid];
  else                t1J[tid - 128] = top1a[bj * 128 + tid - 128];
  if (mode != 0) {
    #pragma unroll
    for (int e = 0; e < 8; ++e) {
      int flat = tid + e * 256;
      int row = flat & 127, w = flat >> 7;
      bsJ[w * 128 + row] = bits[(size_t)(bj * 128 + row) * 16 + w];
    }
  }
  if (mode == 3) {
    #pragma unroll
    for (int e = 0; e < 8; ++e) {
      int flat = tid + e * 256;
      int row = flat & 127, w = flat >> 7;
      bsI[w * 128 + row] = bits[(size_t)(bi * 128 + row) * 16 + w];
    }
  }

  floatx4 acc[4][4];
  floatx4 zero = {0.f, 0.f, 0.f, 0.f};
  #pragma unroll
  for (int ti = 0; ti < 4; ++ti)
    #pragma unroll
    for (int tj = 0; tj < 4; ++tj) acc[ti][tj] = zero;

  const __bf16* Abase = featBF + (size_t)bi * 128 * DIM;
  const __bf16* Bbase = featBF + (size_t)bj * 128 * DIM;

  for (int kt = 0; kt < DIM; kt += 32) {
    __syncthreads();
    #pragma unroll
    for (int t = 0; t < 2; ++t) {
      int idx = tid + t * 256;
      int rw = idx >> 2, cc = (idx & 3) * 8;
      *(bf16x8*)&As[rw * LDK + cc] = *(const bf16x8*)&Abase[(size_t)rw * DIM + kt + cc];
      *(bf16x8*)&Bs[rw * LDK + cc] = *(const bf16x8*)&Bbase[(size_t)rw * DIM + kt + cc];
    }
    __syncthreads();
    bf16x8 afr[4], bfr[4];
    #pragma unroll
    for (int ti = 0; ti < 4; ++ti)
      afr[ti] = *(bf16x8*)&As[(wi * 64 + ti * 16 + lc) * LDK + lr * 8];
    #pragma unroll
    for (int tj = 0; tj < 4; ++tj)
      bfr[tj] = *(bf16x8*)&Bs[(wj * 64 + tj * 16 + lc) * LDK + lr * 8];
    #pragma unroll
    for (int ti = 0; ti < 4; ++ti)
      #pragma unroll
      for (int tj = 0; tj < 4; ++tj)
        acc[ti][tj] = __builtin_amdgcn_mfma_f32_16x16x32_bf16(afr[ti], bfr[tj], acc[ti][tj], 0, 0, 0);
  }
  __syncthreads();

  int tJv[4];
  #pragma unroll
  for (int tj = 0; tj < 4; ++tj) tJv[tj] = t1J[wj * 64 + tj * 16 + lc];

  float cs[4] = {0.f, 0.f, 0.f, 0.f};
  #pragma unroll
  for (int ti = 0; ti < 4; ++ti) {
    int ibase = wi * 64 + ti * 16 + lr * 4;
    unsigned inter[16];
    if (mode == 0) {
      #pragma unroll
      for (int rr = 0; rr < 4; ++rr) {
        int tI = t1I[ibase + rr];
        #pragma unroll
        for (int tj = 0; tj < 4; ++tj) inter[rr * 4 + tj] = (tI == tJv[tj]);
      }
    } else if (mode == 1) {
      #pragma unroll
      for (int rr = 0; rr < 4; ++rr) {
        int tI = t1I[ibase + rr];
        int w = tI >> 6, bb = tI & 63;
        #pragma unroll
        for (int tj = 0; tj < 4; ++tj) {
          ull word = bsJ[w * 128 + wj * 64 + tj * 16 + lc];
          inter[rr * 4 + tj] = (unsigned)((word >> bb) & 1ULL);
        }
      }
    } else {
      #pragma unroll
      for (int q = 0; q < 16; ++q) inter[q] = 0u;
      #pragma unroll
      for (int w = 0; w < 16; ++w) {
        ull2 a01 = *(const ull2*)&bsI[w * 128 + ibase];
        ull2 a23 = *(const ull2*)&bsI[w * 128 + ibase + 2];
        ull aw[4] = {a01[0], a01[1], a23[0], a23[1]};
        ull bw[4];
        #pragma unroll
        for (int tj = 0; tj < 4; ++tj) bw[tj] = bsJ[w * 128 + wj * 64 + tj * 16 + lc];
        #pragma unroll
        for (int rr = 0; rr < 4; ++rr)
          #pragma unroll
          for (int tj = 0; tj < 4; ++tj) {
            ull t = aw[rr] & bw[tj];
            inter[rr * 4 + tj] |= (unsigned)(t | (t >> 32));
          }
      }
    }
    float rs[4] = {0.f, 0.f, 0.f, 0.f};
    #pragma unroll
    for (int rr = 0; rr < 4; ++rr)
      #pragma unroll
      for (int tj = 0; tj < 4; ++tj) {
        float sim = acc[ti][tj][rr];
        sim = fminf(sim, 1.0f);
        float e_ = ((inter[rr * 4 + tj] == 0u) && (sim >= 1e-6f)) ? __expf(sim) : 0.f;
        rs[rr] += e_;
        cs[tj] += e_;
      }
    #pragma unroll
    for (int m = 1; m < 16; m <<= 1)
      #pragma unroll
      for (int rr = 0; rr < 4; ++rr) rs[rr] += __shfl_xor(rs[rr], m);
    if (lc == 0) {
      #pragma unroll
      for (int rr = 0; rr < 4; ++rr)
        atomicAdd(&S[(size_t)bi * 128 + ibase + rr], rs[rr]);
    }
  }
  if (bi != bj) {
    #pragma unroll
    for (int tj = 0; tj < 4; ++tj) {
      cs[tj] += __shfl_xor(cs[tj], 16);
      cs[tj] += __shfl_xor(cs[tj], 32);
    }
    if (lr == 0) {
      #pragma unroll
      for (int tj = 0; tj < 4; ++tj)
        atomicAdd(&S[(size_t)bj * 128 + wj * 64 + tj * 16 + lc], cs[tj]);
    }
  }
}

// ---------------- KF: final reduction — fp32 out -----------------------------
__global__ __launch_bounds__(1024) void kf_final_v7(const float* __restrict__ possim,
                                                    const float* __restrict__ scsim,
                                                    const float* __restrict__ S,
                                                    const int* __restrict__ counters,
                                                    float* __restrict__ out) {
  __shared__ float red[1024];
  int tid = threadIdx.x;
  int nconf = counters[3];
  float local = 0.f;
  for (int i = tid; i < N_ROWS; i += 1024) {
    float p = (i < nconf) ? possim[i] : scsim[i];
    p = fminf(fmaxf(p, -1.1f), 1.1f);      // |pos|<=1 math bound (safety)
    float s = fmaxf(S[i], 0.0f);
    local += logf(expf(p) + s) - p;        // -logp[:,0]
  }
  red[tid] = local;
  __syncthreads();
  for (int s = 512; s > 0; s >>= 1) {
    if (tid < s) red[tid] += red[tid + s];
    __syncthreads();
  }
  if (tid == 0) {
    float loss = red[0] / (float)N_ROWS;
    int scc = counters[0], dn = counters[1];
    float scn = (dn > 0) ? ((float)scc / (float)(dn > 1 ? dn : 1)) : 0.f;
    out[0] = loss;
    out[1] = scn;
  }
}

extern "C" void kernel_launch(void* const* d_in, const int* in_sizes, int n_in,
                              void* d_out, int out_size, void* d_ws, size_t ws_size,
                              hipStream_t stream) {
  const float* feature   = (const float*)d_in[0];
  const float* proxy_raw = (const float*)d_in[1];
  const float* cP        = (const float*)d_in[2];
  const float* prob      = (const float*)d_in[3];
  const int*   conf      = (const int*)d_in[4];
  float* out = (float*)d_out;

  size_t need = (size_t)N_ROWS * DIM * 2      // featBF    8 MB
              + (size_t)C_CLSN * DIM * 4      // proj fp32 2 MB
              + (size_t)C_PAD * DIM * 2       // proxyBF   1 MB
              + (size_t)N_ROWS * 16 * 8       // bits      1 MB
              + (size_t)N_ROWS * 4            // possim
              + (size_t)N_ROWS * 4            // S
              + (size_t)N_ROWS * 4            // scsim
              + 256                           // counters
              + (size_t)N_ROWS * 4            // perm
              + (size_t)N_ROWS * 4;           // top1a
  if (ws_size < need) return;

  char* ws = (char*)d_ws;
  __bf16* featBF  = (__bf16*)ws;  ws += (size_t)N_ROWS * DIM * 2;
  float* proj     = (float*)ws;   ws += (size_t)C_CLSN * DIM * 4;
  __bf16* proxyBF = (__bf16*)ws;  ws += (size_t)C_PAD * DIM * 2;
  ull* bits       = (ull*)ws;     ws += (size_t)N_ROWS * 16 * 8;
  float* possim   = (float*)ws;   ws += (size_t)N_ROWS * 4;
  float* S        = (float*)ws;   ws += (size_t)N_ROWS * 4;   // S, scsim, counters contiguous
  float* scsim    = (float*)ws;   ws += (size_t)N_ROWS * 4;
  int* counters   = (int*)ws;     ws += 256;  // [0]=sc_count [1]=denom [2]=cmode [3]=nconf
  int* perm       = (int*)ws;     ws += (size_t)N_ROWS * 4;
  int* top1a      = (int*)ws;     ws += (size_t)N_ROWS * 4;

  hipMemsetAsync(S, 0, (size_t)N_ROWS * 8 + 256, stream);  // zero S + scsim + counters
  kz_detect_v7<<<1, 256, 0, stream>>>(conf, &counters[2]);
  kp_perm_v7<<<1, 1024, 0, stream>>>(conf, &counters[2], perm, counters);
  kd_prob_v7<<<N_ROWS / 4, 256, 0, stream>>>(prob, perm, bits, top1a, counters);
  ka_featnorm_v7<<<N_ROWS, 64, 0, stream>>>(feature, perm, featBF);
  kb_proj_v7<<<C_CLSN / 8, 256, 0, stream>>>(proxy_raw, cP, proj);
  kc_norm_v7<<<C_PAD, 64, 0, stream>>>(proj, proxyBF);
  kg_pgemm_v7<<<64 * 8, 256, 0, stream>>>(featBF, proxyBF, prob, perm, top1a, scsim, possim);
  ke_sim_v7<<<2080, 256, 0, stream>>>(featBF, bits, top1a, counters, S);
  kf_final_v7<<<1, 1024, 0, stream>>>(possim, scsim, S, counters, out);
}

// Round 8
// 410.327 us; speedup vs baseline: 1.1369x; 1.1369x over previous
//
#include <hip/hip_runtime.h>
#include <hip/hip_bf16.h>

#define N_ROWS 8192
#define DIM 512
#define C_CLSN 1000
#define C_PAD 1024
#define LOW_THRE (1.0f / 1000.0f)
#define LDK 40   // padded LDS leading dim (bf16 elems) to break bank conflicts

typedef __bf16 bf16x8 __attribute__((ext_vector_type(8)));
typedef float floatx4 __attribute__((ext_vector_type(4)));
typedef unsigned long long ull;
typedef ull ull2 __attribute__((ext_vector_type(2)));

// ---------------- KZP: detect conf storage + stable partition (fused) --------
__global__ __launch_bounds__(1024) void kzp_v8(const int* __restrict__ conf,
                                               int* __restrict__ perm,
                                               int* __restrict__ counters) {
  int tid = threadIdx.x;
  __shared__ int sc[1024];
  __shared__ int sbad, sodd1, seven1, smode;
  if (tid == 0) { sbad = 0; sodd1 = 0; seven1 = 0; }
  __syncthreads();
  for (int i = tid; i < 2048; i += 1024) {
    int v = conf[i];
    if (v != 0 && v != 1) atomicOr(&sbad, 1);
    if (v == 1) { if (i & 1) atomicAdd(&sodd1, 1); else atomicAdd(&seven1, 1); }
  }
  __syncthreads();
  if (tid == 0) {
    int mode = 0;                                // int32 0/1
    if (sbad) mode = 1;                          // packed uint8 bools
    else if (seven1 > 0 && sodd1 == 0) mode = 2; // int64 0/1
    smode = mode;
  }
  __syncthreads();
  int mode = smode;
  int r0 = tid * 8;
  int f[8]; int cnt = 0;
  #pragma unroll
  for (int k = 0; k < 8; ++k) {
    int r = r0 + k;
    bool c;
    if (mode == 1)      c = ((const unsigned char*)conf)[r] != 0;
    else if (mode == 2) c = ((const long long*)conf)[r] != 0;
    else                c = conf[r] != 0;
    f[k] = c ? 1 : 0; cnt += f[k];
  }
  sc[tid] = cnt;
  __syncthreads();
  for (int off = 1; off < 1024; off <<= 1) {    // Hillis-Steele inclusive scan
    int v = (tid >= off) ? sc[tid - off] : 0;
    __syncthreads();
    sc[tid] += v;
    __syncthreads();
  }
  int incl = sc[tid];
  int excl = incl - cnt;
  int total = sc[1023];
  if (tid == 0) counters[3] = total;
  int cpos = excl;
  int npos = total + (r0 - excl);
  #pragma unroll
  for (int k = 0; k < 8; ++k) {
    if (f[k]) perm[cpos++] = r0 + k;
    else      perm[npos++] = r0 + k;
  }
}

// ---------------- KDA: prob scan (bits/top1/counters) + feat normalize -------
// wave per row; 4 rows per block
__global__ __launch_bounds__(256) void kda_v8(const float* __restrict__ prob,
                                              const float* __restrict__ feature,
                                              const int* __restrict__ perm,
                                              ull* __restrict__ bits,
                                              int* __restrict__ top1a,
                                              __bf16* __restrict__ featBF,
                                              int* counters) {
  int wv = threadIdx.x >> 6, lane = threadIdx.x & 63;
  int p = blockIdx.x * 4 + wv;
  int orig = perm[p];
  bool is_conf = p < counters[3];              // partitioned: conf rows first
  // ---- prob part ----
  const float* pr = prob + (size_t)orig * C_CLSN;
  float bv = -1e30f; int bidx = 0x7fffffff;
  int cnt = 0;
  ull myword = 0ULL;
  #pragma unroll
  for (int pass = 0; pass < 16; ++pass) {
    int c = pass * 64 + lane;
    float pv = (c < C_CLSN) ? pr[c] : -1.0f;
    if (pv > bv) { bv = pv; bidx = c; }        // ascending: keeps first max
    ull m = __ballot((c < C_CLSN) && (pv > LOW_THRE));
    cnt += (int)__popcll(m);
    if (lane == pass) myword = m;
  }
  #pragma unroll
  for (int m = 1; m < 64; m <<= 1) {           // wave argmax, first-occurrence
    float ov = __shfl_xor(bv, m); int oi = __shfl_xor(bidx, m);
    if (ov > bv || (ov == bv && oi < bidx)) { bv = ov; bidx = oi; }
  }
  int top1 = bidx;
  if (is_conf && lane < 16)
    myword = (lane == (top1 >> 6)) ? (1ULL << (top1 & 63)) : 0ULL;
  if (lane < 16) bits[(size_t)p * 16 + lane] = myword;
  if (lane == 0) {
    top1a[p] = top1;
    if (!is_conf) {
      atomicAdd(&counters[0], cnt);            // sc_count
      atomicAdd(&counters[1], 1);              // denom
    }
  }
  // ---- feature normalize part ----
  const float* fr = feature + (size_t)orig * DIM;
  int c0 = lane * 8;
  float4 v0 = *(const float4*)(fr + c0);
  float4 v1 = *(const float4*)(fr + c0 + 4);
  float ss = v0.x*v0.x + v0.y*v0.y + v0.z*v0.z + v0.w*v0.w
           + v1.x*v1.x + v1.y*v1.y + v1.z*v1.z + v1.w*v1.w;
  #pragma unroll
  for (int m = 1; m < 64; m <<= 1) ss += __shfl_xor(ss, m);
  float scl = 1.0f / fmaxf(sqrtf(ss), 1e-12f);
  bf16x8 bvx;
  bvx[0] = (__bf16)(v0.x * scl); bvx[1] = (__bf16)(v0.y * scl);
  bvx[2] = (__bf16)(v0.z * scl); bvx[3] = (__bf16)(v0.w * scl);
  bvx[4] = (__bf16)(v1.x * scl); bvx[5] = (__bf16)(v1.y * scl);
  bvx[6] = (__bf16)(v1.z * scl); bvx[7] = (__bf16)(v1.w * scl);
  *(bf16x8*)(featBF + (size_t)p * DIM + c0) = bvx;
}

// ---------------- KBC: proxy projection + normalize -> bf16 (fused) ----------
// block: 8 c-rows x 512 d; rows >= C_CLSN written as zeros (pad to 1024)
__global__ __launch_bounds__(256) void kbc_v8(const float* __restrict__ raw,
                                              const float* __restrict__ cP,
                                              __bf16* __restrict__ proxyBF) {
  int tid = threadIdx.x;
  int c0 = blockIdx.x * 8;
  int d0 = tid, d1 = tid + 256;
  if (c0 >= C_CLSN) {                          // zero-pad rows
    #pragma unroll
    for (int cc = 0; cc < 8; ++cc) {
      proxyBF[(size_t)(c0 + cc) * DIM + d0] = (__bf16)0.f;
      proxyBF[(size_t)(c0 + cc) * DIM + d1] = (__bf16)0.f;
    }
    return;
  }
  __shared__ float sraw[8 * DIM];  // 16 KB
  __shared__ float red[8 * 256];   // 8 KB
  for (int idx = tid; idx < 8 * DIM; idx += 256)
    sraw[idx] = raw[(size_t)c0 * DIM + idx];
  __syncthreads();
  float acc0[8], acc1[8];
  #pragma unroll
  for (int cc = 0; cc < 8; ++cc) { acc0[cc] = 0.f; acc1[cc] = 0.f; }
  for (int k = 0; k < DIM; k += 4) {
    float4 w0 = *(const float4*)&cP[(size_t)d0 * DIM + k];
    float4 w1 = *(const float4*)&cP[(size_t)d1 * DIM + k];
    #pragma unroll
    for (int cc = 0; cc < 8; ++cc) {
      const float* sr = &sraw[cc * DIM + k];
      acc0[cc] += sr[0]*w0.x + sr[1]*w0.y + sr[2]*w0.z + sr[3]*w0.w;
      acc1[cc] += sr[0]*w1.x + sr[1]*w1.y + sr[2]*w1.z + sr[3]*w1.w;
    }
  }
  #pragma unroll
  for (int cc = 0; cc < 8; ++cc)
    red[cc * 256 + tid] = acc0[cc]*acc0[cc] + acc1[cc]*acc1[cc];
  __syncthreads();
  for (int s = 128; s > 0; s >>= 1) {
    if (tid < s)
      #pragma unroll
      for (int cc = 0; cc < 8; ++cc)
        red[cc * 256 + tid] += red[cc * 256 + tid + s];
    __syncthreads();
  }
  #pragma unroll
  for (int cc = 0; cc < 8; ++cc) {
    float scl = 1.0f / fmaxf(sqrtf(red[cc * 256]), 1e-12f);
    proxyBF[(size_t)(c0 + cc) * DIM + d0] = (__bf16)(acc0[cc] * scl);
    proxyBF[(size_t)(c0 + cc) * DIM + d1] = (__bf16)(acc1[cc] * scl);
  }
}

// ---------------- KG: P = feat @ proxy^T, fused pos-pair epilogue ------------
__global__ __launch_bounds__(256) void kg_pgemm_v8(const __bf16* __restrict__ featBF,
                                                   const __bf16* __restrict__ proxyBF,
                                                   const float* __restrict__ prob,
                                                   const int* __restrict__ perm,
                                                   const int* __restrict__ top1a,
                                                   float* __restrict__ scsim,
                                                   float* __restrict__ possim) {
  __shared__ __align__(16) __bf16 As[128 * LDK];
  __shared__ __align__(16) __bf16 Bs[128 * LDK];
  __shared__ int pO[128], t1r[128];

  int bi = blockIdx.x >> 3;     // 64 row-tiles
  int bj = blockIdx.x & 7;      // 8 class-tiles

  int tid = threadIdx.x;
  int wv = tid >> 6, lane = tid & 63;
  int wi = wv >> 1, wj = wv & 1;
  int lr = lane >> 4, lc = lane & 15;

  if (tid < 128) { pO[tid] = perm[bi * 128 + tid]; t1r[tid] = top1a[bi * 128 + tid]; }

  floatx4 acc[4][4];
  floatx4 zero = {0.f, 0.f, 0.f, 0.f};
  #pragma unroll
  for (int ti = 0; ti < 4; ++ti)
    #pragma unroll
    for (int tj = 0; tj < 4; ++tj) acc[ti][tj] = zero;

  const __bf16* Abase = featBF + (size_t)bi * 128 * DIM;
  const __bf16* Bbase = proxyBF + (size_t)bj * 128 * DIM;

  for (int kt = 0; kt < DIM; kt += 32) {
    __syncthreads();
    #pragma unroll
    for (int t = 0; t < 2; ++t) {
      int idx = tid + t * 256;
      int rw = idx >> 2, cc = (idx & 3) * 8;
      *(bf16x8*)&As[rw * LDK + cc] = *(const bf16x8*)&Abase[(size_t)rw * DIM + kt + cc];
      *(bf16x8*)&Bs[rw * LDK + cc] = *(const bf16x8*)&Bbase[(size_t)rw * DIM + kt + cc];
    }
    __syncthreads();
    bf16x8 afr[4], bfr[4];
    #pragma unroll
    for (int ti = 0; ti < 4; ++ti)
      afr[ti] = *(bf16x8*)&As[(wi * 64 + ti * 16 + lc) * LDK + lr * 8];
    #pragma unroll
    for (int tj = 0; tj < 4; ++tj)
      bfr[tj] = *(bf16x8*)&Bs[(wj * 64 + tj * 16 + lc) * LDK + lr * 8];
    #pragma unroll
    for (int ti = 0; ti < 4; ++ti)
      #pragma unroll
      for (int tj = 0; tj < 4; ++tj)
        acc[ti][tj] = __builtin_amdgcn_mfma_f32_16x16x32_bf16(afr[ti], bfr[tj], acc[ti][tj], 0, 0, 0);
  }
  __syncthreads();

  #pragma unroll
  for (int ti = 0; ti < 4; ++ti) {
    int ibase = wi * 64 + ti * 16 + lr * 4;   // C/D: row=(lane>>4)*4+reg, col=lane&15
    float rs[4] = {0.f, 0.f, 0.f, 0.f};
    #pragma unroll
    for (int rr = 0; rr < 4; ++rr) {
      int il = ibase + rr;
      int orig = pO[il];
      int t1 = t1r[il];
      const float* prow = prob + (size_t)orig * C_CLSN;
      #pragma unroll
      for (int tj = 0; tj < 4; ++tj) {
        int c = bj * 128 + wj * 64 + tj * 16 + lc;
        float P = acc[ti][tj][rr];
        float pv = (c < C_CLSN) ? prow[c] : 0.f;
        if (pv > LOW_THRE) rs[rr] += pv * P;
        if (c == t1) possim[bi * 128 + il] = P;   // single writer grid-wide
      }
    }
    #pragma unroll
    for (int m = 1; m < 16; m <<= 1)
      #pragma unroll
      for (int rr = 0; rr < 4; ++rr) rs[rr] += __shfl_xor(rs[rr], m);
    if (lc == 0) {
      #pragma unroll
      for (int rr = 0; rr < 4; ++rr)
        atomicAdd(&scsim[bi * 128 + ibase + rr], rs[rr]);
    }
  }
}

// ---------------- KE: sim GEMM + mask + sum(exp) — 512 threads ---------------
// 8 waves, each 64x32 sub-tile: acc[4][2] (32 VGPR) to double occupancy.
// bsJ aliased over As/Bs (staged post-K-loop). Block order LCG-swizzled.
__global__ __launch_bounds__(512) void ke_sim_v8(const __bf16* __restrict__ featBF,
                                                 const ull* __restrict__ bits,
                                                 const int* __restrict__ top1a,
                                                 const int* __restrict__ counters_ro,
                                                 float* __restrict__ S) {
  __shared__ __align__(16) char smem[38912];
  __bf16* As = (__bf16*)smem;                 // 10240 B
  __bf16* Bs = (__bf16*)(smem + 10240);       // 10240 B
  ull* bsJ   = (ull*)smem;                    // 16384 B, aliases As∪Bs post-loop
  ull* bsI   = (ull*)(smem + 20480);          // 16384 B (dedicated)
  int* t1I   = (int*)(smem + 36864);          // 512 B
  int* t1J   = (int*)(smem + 37376);          // 512 B

  // LCG swizzle to interleave heavy (mode-3) and light tiles across rounds
  int b = (int)(((long long)blockIdx.x * 997) % 2080);
  int bi = 0, rem = b;
  while (rem >= 64 - bi) { rem -= 64 - bi; bi++; }
  int bj = bi + rem;

  int nconf = counters_ro[3];
  bool allcI = (bi * 128 + 128) <= nconf;
  bool allcJ = (bj * 128 + 128) <= nconf;
  int mode = allcJ ? 0 : (allcI ? 1 : 3);     // bi<=bj + conf-first => allcJ -> allcI

  int tid = threadIdx.x;
  int wv = tid >> 6, lane = tid & 63;
  int wi = wv >> 2, wj = wv & 3;              // 2x4 wave grid: 64 rows x 32 cols each
  int lr = lane >> 4, lc = lane & 15;

  if (tid < 128)      t1I[tid]       = top1a[bi * 128 + tid];
  else if (tid < 256) t1J[tid - 128] = top1a[bj * 128 + tid - 128];
  if (mode == 3) {    // bsI is dedicated LDS: stage before K-loop
    #pragma unroll
    for (int e = 0; e < 4; ++e) {
      int flat = tid + e * 512;
      int row = flat & 127, w = flat >> 7;
      bsI[w * 128 + row] = bits[(size_t)(bi * 128 + row) * 16 + w];
    }
  }

  floatx4 acc[4][2];
  floatx4 zero = {0.f, 0.f, 0.f, 0.f};
  #pragma unroll
  for (int ti = 0; ti < 4; ++ti)
    #pragma unroll
    for (int tj = 0; tj < 2; ++tj) acc[ti][tj] = zero;

  const __bf16* Abase = featBF + (size_t)bi * 128 * DIM;
  const __bf16* Bbase = featBF + (size_t)bj * 128 * DIM;

  for (int kt = 0; kt < DIM; kt += 32) {
    __syncthreads();
    {
      int rw = tid >> 2, cc = (tid & 3) * 8;  // 512 threads: full tile in one pass
      *(bf16x8*)&As[rw * LDK + cc] = *(const bf16x8*)&Abase[(size_t)rw * DIM + kt + cc];
      *(bf16x8*)&Bs[rw * LDK + cc] = *(const bf16x8*)&Bbase[(size_t)rw * DIM + kt + cc];
    }
    __syncthreads();
    bf16x8 afr[4], bfr[2];
    #pragma unroll
    for (int ti = 0; ti < 4; ++ti)
      afr[ti] = *(bf16x8*)&As[(wi * 64 + ti * 16 + lc) * LDK + lr * 8];
    #pragma unroll
    for (int tj = 0; tj < 2; ++tj)
      bfr[tj] = *(bf16x8*)&Bs[(wj * 32 + tj * 16 + lc) * LDK + lr * 8];
    #pragma unroll
    for (int ti = 0; ti < 4; ++ti)
      #pragma unroll
      for (int tj = 0; tj < 2; ++tj)
        acc[ti][tj] = __builtin_amdgcn_mfma_f32_16x16x32_bf16(afr[ti], bfr[tj], acc[ti][tj], 0, 0, 0);
  }
  __syncthreads();              // all waves done reading As/Bs
  if (mode != 0) {              // stage bsJ into the aliased region
    #pragma unroll
    for (int e = 0; e < 4; ++e) {
      int flat = tid + e * 512;
      int row = flat & 127, w = flat >> 7;
      bsJ[w * 128 + row] = bits[(size_t)(bj * 128 + row) * 16 + w];
    }
  }
  __syncthreads();

  int tJv[2];
  #pragma unroll
  for (int tj = 0; tj < 2; ++tj) tJv[tj] = t1J[wj * 32 + tj * 16 + lc];

  float cs[2] = {0.f, 0.f};     // mirror column partial sums (this wave's rows)
  #pragma unroll
  for (int ti = 0; ti < 4; ++ti) {
    int ibase = wi * 64 + ti * 16 + lr * 4;
    unsigned inter[8];
    if (mode == 0) {            // conf x conf: intersect <=> same top1
      #pragma unroll
      for (int rr = 0; rr < 4; ++rr) {
        int tI = t1I[ibase + rr];
        #pragma unroll
        for (int tj = 0; tj < 2; ++tj) inter[rr * 2 + tj] = (tI == tJv[tj]);
      }
    } else if (mode == 1) {     // conf-I: probe J's bitset with top1_i
      #pragma unroll
      for (int rr = 0; rr < 4; ++rr) {
        int tI = t1I[ibase + rr];
        int w = tI >> 6, bb = tI & 63;
        #pragma unroll
        for (int tj = 0; tj < 2; ++tj) {
          ull word = bsJ[w * 128 + wj * 32 + tj * 16 + lc];
          inter[rr * 2 + tj] = (unsigned)((word >> bb) & 1ULL);
        }
      }
    } else {                    // general: full 1000-bit AND
      #pragma unroll
      for (int q = 0; q < 8; ++q) inter[q] = 0u;
      #pragma unroll
      for (int w = 0; w < 16; ++w) {
        ull2 a01 = *(const ull2*)&bsI[w * 128 + ibase];
        ull2 a23 = *(const ull2*)&bsI[w * 128 + ibase + 2];
        ull aw[4] = {a01[0], a01[1], a23[0], a23[1]};
        ull bw[2];
        #pragma unroll
        for (int tj = 0; tj < 2; ++tj) bw[tj] = bsJ[w * 128 + wj * 32 + tj * 16 + lc];
        #pragma unroll
        for (int rr = 0; rr < 4; ++rr)
          #pragma unroll
          for (int tj = 0; tj < 2; ++tj) {
            ull t = aw[rr] & bw[tj];
            inter[rr * 2 + tj] |= (unsigned)(t | (t >> 32));
          }
      }
    }
    float rs[4] = {0.f, 0.f, 0.f, 0.f};
    #pragma unroll
    for (int rr = 0; rr < 4; ++rr)
      #pragma unroll
      for (int tj = 0; tj < 2; ++tj) {
        float sim = acc[ti][tj][rr];
        sim = fminf(sim, 1.0f);   // unit rows: math no-op
        float e_ = ((inter[rr * 2 + tj] == 0u) && (sim >= 1e-6f)) ? __expf(sim) : 0.f;
        rs[rr] += e_;
        cs[tj] += e_;
      }
    #pragma unroll
    for (int m = 1; m < 16; m <<= 1)
      #pragma unroll
      for (int rr = 0; rr < 4; ++rr) rs[rr] += __shfl_xor(rs[rr], m);
    if (lc == 0) {
      #pragma unroll
      for (int rr = 0; rr < 4; ++rr)
        atomicAdd(&S[(size_t)bi * 128 + ibase + rr], rs[rr]);
    }
  }
  if (bi != bj) {   // mirror: (j,i) identical by symmetry -> column sums
    #pragma unroll
    for (int tj = 0; tj < 2; ++tj) {
      cs[tj] += __shfl_xor(cs[tj], 16);   // reduce over lr
      cs[tj] += __shfl_xor(cs[tj], 32);
    }
    if (lr == 0) {
      #pragma unroll
      for (int tj = 0; tj < 2; ++tj)
        atomicAdd(&S[(size_t)bj * 128 + wj * 32 + tj * 16 + lc], cs[tj]);
    }
  }
}

// ---------------- KF: final reduction — fp32 out -----------------------------
__global__ __launch_bounds__(1024) void kf_final_v8(const float* __restrict__ possim,
                                                    const float* __restrict__ scsim,
                                                    const float* __restrict__ S,
                                                    const int* __restrict__ counters,
                                                    float* __restrict__ out) {
  __shared__ float red[1024];
  int tid = threadIdx.x;
  int nconf = counters[3];
  float local = 0.f;
  for (int i = tid; i < N_ROWS; i += 1024) {
    float p = (i < nconf) ? possim[i] : scsim[i];
    p = fminf(fmaxf(p, -1.1f), 1.1f);      // |pos|<=1 math bound (safety)
    float s = fmaxf(S[i], 0.0f);
    local += logf(expf(p) + s) - p;        // -logp[:,0]
  }
  red[tid] = local;
  __syncthreads();
  for (int s = 512; s > 0; s >>= 1) {
    if (tid < s) red[tid] += red[tid + s];
    __syncthreads();
  }
  if (tid == 0) {
    float loss = red[0] / (float)N_ROWS;
    int scc = counters[0], dn = counters[1];
    float scn = (dn > 0) ? ((float)scc / (float)(dn > 1 ? dn : 1)) : 0.f;
    out[0] = loss;
    out[1] = scn;
  }
}

extern "C" void kernel_launch(void* const* d_in, const int* in_sizes, int n_in,
                              void* d_out, int out_size, void* d_ws, size_t ws_size,
                              hipStream_t stream) {
  const float* feature   = (const float*)d_in[0];
  const float* proxy_raw = (const float*)d_in[1];
  const float* cP        = (const float*)d_in[2];
  const float* prob      = (const float*)d_in[3];
  const int*   conf      = (const int*)d_in[4];
  float* out = (float*)d_out;

  size_t need = (size_t)N_ROWS * DIM * 2      // featBF    8 MB
              + (size_t)C_PAD * DIM * 2       // proxyBF   1 MB
              + (size_t)N_ROWS * 16 * 8       // bits      1 MB
              + (size_t)N_ROWS * 4            // possim
              + (size_t)N_ROWS * 4            // S
              + (size_t)N_ROWS * 4            // scsim
              + 256                           // counters
              + (size_t)N_ROWS * 4            // perm
              + (size_t)N_ROWS * 4;           // top1a
  if (ws_size < need) return;

  char* ws = (char*)d_ws;
  __bf16* featBF  = (__bf16*)ws;  ws += (size_t)N_ROWS * DIM * 2;
  __bf16* proxyBF = (__bf16*)ws;  ws += (size_t)C_PAD * DIM * 2;
  ull* bits       = (ull*)ws;     ws += (size_t)N_ROWS * 16 * 8;
  float* possim   = (float*)ws;   ws += (size_t)N_ROWS * 4;
  float* S        = (float*)ws;   ws += (size_t)N_ROWS * 4;   // S, scsim, counters contiguous
  float* scsim    = (float*)ws;   ws += (size_t)N_ROWS * 4;
  int* counters   = (int*)ws;     ws += 256;  // [0]=sc_count [1]=denom [3]=nconf
  int* perm       = (int*)ws;     ws += (size_t)N_ROWS * 4;
  int* top1a      = (int*)ws;     ws += (size_t)N_ROWS * 4;

  hipMemsetAsync(S, 0, (size_t)N_ROWS * 8 + 256, stream);  // zero S + scsim + counters
  kzp_v8<<<1, 1024, 0, stream>>>(conf, perm, counters);
  kda_v8<<<N_ROWS / 4, 256, 0, stream>>>(prob, feature, perm, bits, top1a, featBF, counters);
  kbc_v8<<<C_PAD / 8, 256, 0, stream>>>(proxy_raw, cP, proxyBF);
  kg_pgemm_v8<<<64 * 8, 256, 0, stream>>>(featBF, proxyBF, prob, perm, top1a, scsim, possim);
  ke_sim_v8<<<2080, 512, 0, stream>>>(featBF, bits, top1a, counters, S);
  kf_final_v8<<<1, 1024, 0, stream>>>(possim, scsim, S, counters, out);
}

// Round 9
// 394.649 us; speedup vs baseline: 1.1821x; 1.0397x over previous
//
#include <hip/hip_runtime.h>
#include <hip/hip_bf16.h>

#define N_ROWS 8192
#define DIM 512
#define C_CLSN 1000
#define C_PAD 1024
#define LOW_THRE (1.0f / 1000.0f)
#define LDK 40    // bf16 LDS leading dim (elems)
#define LDF8 72   // fp8 LDS leading dim (bytes): 72%8==0 for b64 reads, odd bank stride/2

typedef __bf16 bf16x8 __attribute__((ext_vector_type(8)));
typedef float floatx4 __attribute__((ext_vector_type(4)));
typedef unsigned long long ull;
typedef ull ull2 __attribute__((ext_vector_type(2)));

// ---------------- KZP: detect conf storage + stable partition (fused) --------
__global__ __launch_bounds__(1024) void kzp_v9(const int* __restrict__ conf,
                                               int* __restrict__ perm,
                                               int* __restrict__ counters) {
  int tid = threadIdx.x;
  __shared__ int sc[1024];
  __shared__ int sbad, sodd1, seven1, smode;
  if (tid == 0) { sbad = 0; sodd1 = 0; seven1 = 0; }
  __syncthreads();
  for (int i = tid; i < 2048; i += 1024) {
    int v = conf[i];
    if (v != 0 && v != 1) atomicOr(&sbad, 1);
    if (v == 1) { if (i & 1) atomicAdd(&sodd1, 1); else atomicAdd(&seven1, 1); }
  }
  __syncthreads();
  if (tid == 0) {
    int mode = 0;                                // int32 0/1
    if (sbad) mode = 1;                          // packed uint8 bools
    else if (seven1 > 0 && sodd1 == 0) mode = 2; // int64 0/1
    smode = mode;
  }
  __syncthreads();
  int mode = smode;
  int r0 = tid * 8;
  int f[8]; int cnt = 0;
  #pragma unroll
  for (int k = 0; k < 8; ++k) {
    int r = r0 + k;
    bool c;
    if (mode == 1)      c = ((const unsigned char*)conf)[r] != 0;
    else if (mode == 2) c = ((const long long*)conf)[r] != 0;
    else                c = conf[r] != 0;
    f[k] = c ? 1 : 0; cnt += f[k];
  }
  sc[tid] = cnt;
  __syncthreads();
  for (int off = 1; off < 1024; off <<= 1) {    // Hillis-Steele inclusive scan
    int v = (tid >= off) ? sc[tid - off] : 0;
    __syncthreads();
    sc[tid] += v;
    __syncthreads();
  }
  int incl = sc[tid];
  int excl = incl - cnt;
  int total = sc[1023];
  if (tid == 0) counters[3] = total;
  int cpos = excl;
  int npos = total + (r0 - excl);
  #pragma unroll
  for (int k = 0; k < 8; ++k) {
    if (f[k]) perm[cpos++] = r0 + k;
    else      perm[npos++] = r0 + k;
  }
}

// ---------------- KDA: prob scan + feat normalize -> bf16 AND fp8 ------------
__global__ __launch_bounds__(256) void kda_v9(const float* __restrict__ prob,
                                              const float* __restrict__ feature,
                                              const int* __restrict__ perm,
                                              ull* __restrict__ bits,
                                              int* __restrict__ top1a,
                                              __bf16* __restrict__ featBF,
                                              unsigned char* __restrict__ featF8,
                                              int* counters) {
  int wv = threadIdx.x >> 6, lane = threadIdx.x & 63;
  int p = blockIdx.x * 4 + wv;
  int orig = perm[p];
  bool is_conf = p < counters[3];              // partitioned: conf rows first
  // ---- prob part ----
  const float* pr = prob + (size_t)orig * C_CLSN;
  float bv = -1e30f; int bidx = 0x7fffffff;
  int cnt = 0;
  ull myword = 0ULL;
  #pragma unroll
  for (int pass = 0; pass < 16; ++pass) {
    int c = pass * 64 + lane;
    float pv = (c < C_CLSN) ? pr[c] : -1.0f;
    if (pv > bv) { bv = pv; bidx = c; }        // ascending: keeps first max
    ull m = __ballot((c < C_CLSN) && (pv > LOW_THRE));
    cnt += (int)__popcll(m);
    if (lane == pass) myword = m;
  }
  #pragma unroll
  for (int m = 1; m < 64; m <<= 1) {           // wave argmax, first-occurrence
    float ov = __shfl_xor(bv, m); int oi = __shfl_xor(bidx, m);
    if (ov > bv || (ov == bv && oi < bidx)) { bv = ov; bidx = oi; }
  }
  int top1 = bidx;
  if (is_conf && lane < 16)
    myword = (lane == (top1 >> 6)) ? (1ULL << (top1 & 63)) : 0ULL;
  if (lane < 16) bits[(size_t)p * 16 + lane] = myword;
  if (lane == 0) {
    top1a[p] = top1;
    if (!is_conf) {
      atomicAdd(&counters[0], cnt);            // sc_count
      atomicAdd(&counters[1], 1);              // denom
    }
  }
  // ---- feature normalize part ----
  const float* fr = feature + (size_t)orig * DIM;
  int c0 = lane * 8;
  float4 v0 = *(const float4*)(fr + c0);
  float4 v1 = *(const float4*)(fr + c0 + 4);
  float ss = v0.x*v0.x + v0.y*v0.y + v0.z*v0.z + v0.w*v0.w
           + v1.x*v1.x + v1.y*v1.y + v1.z*v1.z + v1.w*v1.w;
  #pragma unroll
  for (int m = 1; m < 64; m <<= 1) ss += __shfl_xor(ss, m);
  float scl = 1.0f / fmaxf(sqrtf(ss), 1e-12f);
  float x0 = v0.x*scl, x1 = v0.y*scl, x2 = v0.z*scl, x3 = v0.w*scl;
  float x4 = v1.x*scl, x5 = v1.y*scl, x6 = v1.z*scl, x7 = v1.w*scl;
  bf16x8 bvx;
  bvx[0] = (__bf16)x0; bvx[1] = (__bf16)x1; bvx[2] = (__bf16)x2; bvx[3] = (__bf16)x3;
  bvx[4] = (__bf16)x4; bvx[5] = (__bf16)x5; bvx[6] = (__bf16)x6; bvx[7] = (__bf16)x7;
  *(bf16x8*)(featBF + (size_t)p * DIM + c0) = bvx;
  int lo = __builtin_amdgcn_cvt_pk_fp8_f32(x0, x1, 0, false);
  lo = __builtin_amdgcn_cvt_pk_fp8_f32(x2, x3, lo, true);
  int hi = __builtin_amdgcn_cvt_pk_fp8_f32(x4, x5, 0, false);
  hi = __builtin_amdgcn_cvt_pk_fp8_f32(x6, x7, hi, true);
  int2 pk; pk.x = lo; pk.y = hi;
  *(int2*)(featF8 + (size_t)p * DIM + c0) = pk;
}

// ---------------- KBC: proxy projection + normalize -> bf16 (fused) ----------
__global__ __launch_bounds__(256) void kbc_v9(const float* __restrict__ raw,
                                              const float* __restrict__ cP,
                                              __bf16* __restrict__ proxyBF) {
  int tid = threadIdx.x;
  int c0 = blockIdx.x * 8;
  int d0 = tid, d1 = tid + 256;
  if (c0 >= C_CLSN) {                          // zero-pad rows
    #pragma unroll
    for (int cc = 0; cc < 8; ++cc) {
      proxyBF[(size_t)(c0 + cc) * DIM + d0] = (__bf16)0.f;
      proxyBF[(size_t)(c0 + cc) * DIM + d1] = (__bf16)0.f;
    }
    return;
  }
  __shared__ float sraw[8 * DIM];  // 16 KB
  __shared__ float red[8 * 256];   // 8 KB
  for (int idx = tid; idx < 8 * DIM; idx += 256)
    sraw[idx] = raw[(size_t)c0 * DIM + idx];
  __syncthreads();
  float acc0[8], acc1[8];
  #pragma unroll
  for (int cc = 0; cc < 8; ++cc) { acc0[cc] = 0.f; acc1[cc] = 0.f; }
  for (int k = 0; k < DIM; k += 4) {
    float4 w0 = *(const float4*)&cP[(size_t)d0 * DIM + k];
    float4 w1 = *(const float4*)&cP[(size_t)d1 * DIM + k];
    #pragma unroll
    for (int cc = 0; cc < 8; ++cc) {
      const float* sr = &sraw[cc * DIM + k];
      acc0[cc] += sr[0]*w0.x + sr[1]*w0.y + sr[2]*w0.z + sr[3]*w0.w;
      acc1[cc] += sr[0]*w1.x + sr[1]*w1.y + sr[2]*w1.z + sr[3]*w1.w;
    }
  }
  #pragma unroll
  for (int cc = 0; cc < 8; ++cc)
    red[cc * 256 + tid] = acc0[cc]*acc0[cc] + acc1[cc]*acc1[cc];
  __syncthreads();
  for (int s = 128; s > 0; s >>= 1) {
    if (tid < s)
      #pragma unroll
      for (int cc = 0; cc < 8; ++cc)
        red[cc * 256 + tid] += red[cc * 256 + tid + s];
    __syncthreads();
  }
  #pragma unroll
  for (int cc = 0; cc < 8; ++cc) {
    float scl = 1.0f / fmaxf(sqrtf(red[cc * 256]), 1e-12f);
    proxyBF[(size_t)(c0 + cc) * DIM + d0] = (__bf16)(acc0[cc] * scl);
    proxyBF[(size_t)(c0 + cc) * DIM + d1] = (__bf16)(acc1[cc] * scl);
  }
}

// ---------------- KG: P = feat @ proxy^T (bf16), fused pos-pair epilogue -----
// v9: 512 threads, 8 waves of 64x32 -> acc[4][2] (occupancy 2x vs v8)
__global__ __launch_bounds__(512) void kg_pgemm_v9(const __bf16* __restrict__ featBF,
                                                   const __bf16* __restrict__ proxyBF,
                                                   const float* __restrict__ prob,
                                                   const int* __restrict__ perm,
                                                   const int* __restrict__ top1a,
                                                   float* __restrict__ scsim,
                                                   float* __restrict__ possim) {
  __shared__ __align__(16) __bf16 As[128 * LDK];
  __shared__ __align__(16) __bf16 Bs[128 * LDK];
  __shared__ int pO[128], t1r[128];

  int bi = blockIdx.x >> 3;     // 64 row-tiles
  int bj = blockIdx.x & 7;      // 8 class-tiles

  int tid = threadIdx.x;
  int wv = tid >> 6, lane = tid & 63;
  int wi = wv >> 2, wj = wv & 3;   // 2x4 wave grid: 64 rows x 32 cols
  int lr = lane >> 4, lc = lane & 15;

  if (tid < 128) { pO[tid] = perm[bi * 128 + tid]; t1r[tid] = top1a[bi * 128 + tid]; }

  floatx4 acc[4][2];
  floatx4 zero = {0.f, 0.f, 0.f, 0.f};
  #pragma unroll
  for (int ti = 0; ti < 4; ++ti)
    #pragma unroll
    for (int tj = 0; tj < 2; ++tj) acc[ti][tj] = zero;

  const __bf16* Abase = featBF + (size_t)bi * 128 * DIM;
  const __bf16* Bbase = proxyBF + (size_t)bj * 128 * DIM;

  for (int kt = 0; kt < DIM; kt += 32) {
    __syncthreads();
    {
      int rw = tid >> 2, cc = (tid & 3) * 8;  // 512 threads: full tile, one pass
      *(bf16x8*)&As[rw * LDK + cc] = *(const bf16x8*)&Abase[(size_t)rw * DIM + kt + cc];
      *(bf16x8*)&Bs[rw * LDK + cc] = *(const bf16x8*)&Bbase[(size_t)rw * DIM + kt + cc];
    }
    __syncthreads();
    bf16x8 afr[4], bfr[2];
    #pragma unroll
    for (int ti = 0; ti < 4; ++ti)
      afr[ti] = *(bf16x8*)&As[(wi * 64 + ti * 16 + lc) * LDK + lr * 8];
    #pragma unroll
    for (int tj = 0; tj < 2; ++tj)
      bfr[tj] = *(bf16x8*)&Bs[(wj * 32 + tj * 16 + lc) * LDK + lr * 8];
    #pragma unroll
    for (int ti = 0; ti < 4; ++ti)
      #pragma unroll
      for (int tj = 0; tj < 2; ++tj)
        acc[ti][tj] = __builtin_amdgcn_mfma_f32_16x16x32_bf16(afr[ti], bfr[tj], acc[ti][tj], 0, 0, 0);
  }
  __syncthreads();

  #pragma unroll
  for (int ti = 0; ti < 4; ++ti) {
    int ibase = wi * 64 + ti * 16 + lr * 4;   // C/D: row=(lane>>4)*4+reg, col=lane&15
    float rs[4] = {0.f, 0.f, 0.f, 0.f};
    #pragma unroll
    for (int rr = 0; rr < 4; ++rr) {
      int il = ibase + rr;
      int orig = pO[il];
      int t1 = t1r[il];
      const float* prow = prob + (size_t)orig * C_CLSN;
      #pragma unroll
      for (int tj = 0; tj < 2; ++tj) {
        int c = bj * 128 + wj * 32 + tj * 16 + lc;
        float P = acc[ti][tj][rr];
        float pv = (c < C_CLSN) ? prow[c] : 0.f;
        if (pv > LOW_THRE) rs[rr] += pv * P;
        if (c == t1) possim[bi * 128 + il] = P;   // single writer grid-wide
      }
    }
    #pragma unroll
    for (int m = 1; m < 16; m <<= 1)
      #pragma unroll
      for (int rr = 0; rr < 4; ++rr) rs[rr] += __shfl_xor(rs[rr], m);
    if (lc == 0) {
      #pragma unroll
      for (int rr = 0; rr < 4; ++rr)
        atomicAdd(&scsim[bi * 128 + ibase + rr], rs[rr]);
    }
  }
}

// ---------------- KE: sim GEMM in FP8 + mask + sum(exp) ----------------------
// feat quantized to e4m3 (sim err ~0.008 << 0.86 tol). BK=64 -> 8 K-iters.
// featF8 = 4 MB -> fits per-XCD L2. 512 threads, wave = 64x32, acc[4][2].
__global__ __launch_bounds__(512) void ke_sim_v9(const unsigned char* __restrict__ featF8,
                                                 const ull* __restrict__ bits,
                                                 const int* __restrict__ top1a,
                                                 const int* __restrict__ counters_ro,
                                                 float* __restrict__ S) {
  __shared__ __align__(16) char smem[35840];
  unsigned char* As = (unsigned char*)smem;           // 128*72 = 9216 B
  unsigned char* Bs = (unsigned char*)(smem + 9216);  // 9216 B
  ull* bsJ = (ull*)smem;                              // 16384 B, aliases As+Bs post-loop
  ull* bsI = (ull*)(smem + 18432);                    // 16384 B (dedicated)
  int* t1I = (int*)(smem + 34816);                    // 512 B
  int* t1J = (int*)(smem + 35328);                    // 512 B

  // LCG swizzle interleaves heavy (mode-3) and light tiles
  int b = (int)(((long long)blockIdx.x * 997) % 2080);
  int bi = 0, rem = b;
  while (rem >= 64 - bi) { rem -= 64 - bi; bi++; }
  int bj = bi + rem;

  int nconf = counters_ro[3];
  bool allcI = (bi * 128 + 128) <= nconf;
  bool allcJ = (bj * 128 + 128) <= nconf;
  int mode = allcJ ? 0 : (allcI ? 1 : 3);   // bi<=bj + conf-first => allcJ -> allcI

  int tid = threadIdx.x;
  int wv = tid >> 6, lane = tid & 63;
  int wi = wv >> 2, wj = wv & 3;            // 2x4 wave grid: 64 rows x 32 cols
  int lr = lane >> 4, lc = lane & 15;

  if (tid < 128)      t1I[tid]       = top1a[bi * 128 + tid];
  else if (tid < 256) t1J[tid - 128] = top1a[bj * 128 + tid - 128];
  if (mode == 3) {    // bsI dedicated: stage before K-loop
    #pragma unroll
    for (int e = 0; e < 4; ++e) {
      int flat = tid + e * 512;
      int row = flat & 127, w = flat >> 7;
      bsI[w * 128 + row] = bits[(size_t)(bi * 128 + row) * 16 + w];
    }
  }

  floatx4 acc[4][2];
  floatx4 zero = {0.f, 0.f, 0.f, 0.f};
  #pragma unroll
  for (int ti = 0; ti < 4; ++ti)
    #pragma unroll
    for (int tj = 0; tj < 2; ++tj) acc[ti][tj] = zero;

  const unsigned char* Abase = featF8 + (size_t)bi * 128 * DIM;
  const unsigned char* Bbase = featF8 + (size_t)bj * 128 * DIM;

  for (int kt = 0; kt < DIM; kt += 64) {   // 8 iterations
    __syncthreads();
    {
      int rw = tid >> 2, cc = (tid & 3) * 16;   // 128 rows x 4 chunks of 16 B
      *(int4*)&As[rw * LDF8 + cc] = *(const int4*)&Abase[(size_t)rw * DIM + kt + cc];
      *(int4*)&Bs[rw * LDF8 + cc] = *(const int4*)&Bbase[(size_t)rw * DIM + kt + cc];
    }
    __syncthreads();
    // fp8 16x16x32 frag: row = lane&15, k = (lane>>4)*8 + byte (same geom as bf16)
    #pragma unroll
    for (int ks = 0; ks < 2; ++ks) {
      long a_[4], b_[2];
      #pragma unroll
      for (int ti = 0; ti < 4; ++ti)
        a_[ti] = *(const long*)&As[(wi * 64 + ti * 16 + lc) * LDF8 + ks * 32 + lr * 8];
      #pragma unroll
      for (int tj = 0; tj < 2; ++tj)
        b_[tj] = *(const long*)&Bs[(wj * 32 + tj * 16 + lc) * LDF8 + ks * 32 + lr * 8];
      #pragma unroll
      for (int ti = 0; ti < 4; ++ti)
        #pragma unroll
        for (int tj = 0; tj < 2; ++tj)
          acc[ti][tj] = __builtin_amdgcn_mfma_f32_16x16x32_fp8_fp8(a_[ti], b_[tj], acc[ti][tj], 0, 0, 0);
    }
  }
  __syncthreads();              // all waves done reading As/Bs
  if (mode != 0) {              // stage bsJ into the aliased region
    #pragma unroll
    for (int e = 0; e < 4; ++e) {
      int flat = tid + e * 512;
      int row = flat & 127, w = flat >> 7;
      bsJ[w * 128 + row] = bits[(size_t)(bj * 128 + row) * 16 + w];
    }
  }
  __syncthreads();

  int tJv[2];
  #pragma unroll
  for (int tj = 0; tj < 2; ++tj) tJv[tj] = t1J[wj * 32 + tj * 16 + lc];

  float cs[2] = {0.f, 0.f};     // mirror column partial sums
  #pragma unroll
  for (int ti = 0; ti < 4; ++ti) {
    int ibase = wi * 64 + ti * 16 + lr * 4;
    unsigned inter[8];
    if (mode == 0) {            // conf x conf: intersect <=> same top1
      #pragma unroll
      for (int rr = 0; rr < 4; ++rr) {
        int tI = t1I[ibase + rr];
        #pragma unroll
        for (int tj = 0; tj < 2; ++tj) inter[rr * 2 + tj] = (tI == tJv[tj]);
      }
    } else if (mode == 1) {     // conf-I: probe J's bitset with top1_i
      #pragma unroll
      for (int rr = 0; rr < 4; ++rr) {
        int tI = t1I[ibase + rr];
        int w = tI >> 6, bb = tI & 63;
        #pragma unroll
        for (int tj = 0; tj < 2; ++tj) {
          ull word = bsJ[w * 128 + wj * 32 + tj * 16 + lc];
          inter[rr * 2 + tj] = (unsigned)((word >> bb) & 1ULL);
        }
      }
    } else {                    // general: full 1000-bit AND
      #pragma unroll
      for (int q = 0; q < 8; ++q) inter[q] = 0u;
      #pragma unroll
      for (int w = 0; w < 16; ++w) {
        ull2 a01 = *(const ull2*)&bsI[w * 128 + ibase];
        ull2 a23 = *(const ull2*)&bsI[w * 128 + ibase + 2];
        ull aw[4] = {a01[0], a01[1], a23[0], a23[1]};
        ull bw[2];
        #pragma unroll
        for (int tj = 0; tj < 2; ++tj) bw[tj] = bsJ[w * 128 + wj * 32 + tj * 16 + lc];
        #pragma unroll
        for (int rr = 0; rr < 4; ++rr)
          #pragma unroll
          for (int tj = 0; tj < 2; ++tj) {
            ull t = aw[rr] & bw[tj];
            inter[rr * 2 + tj] |= (unsigned)(t | (t >> 32));
          }
      }
    }
    float rs[4] = {0.f, 0.f, 0.f, 0.f};
    #pragma unroll
    for (int rr = 0; rr < 4; ++rr)
      #pragma unroll
      for (int tj = 0; tj < 2; ++tj) {
        float sim = acc[ti][tj][rr];
        sim = fminf(sim, 1.0f);   // unit rows: math no-op
        float e_ = ((inter[rr * 2 + tj] == 0u) && (sim >= 1e-6f)) ? __expf(sim) : 0.f;
        rs[rr] += e_;
        cs[tj] += e_;
      }
    #pragma unroll
    for (int m = 1; m < 16; m <<= 1)
      #pragma unroll
      for (int rr = 0; rr < 4; ++rr) rs[rr] += __shfl_xor(rs[rr], m);
    if (lc == 0) {
      #pragma unroll
      for (int rr = 0; rr < 4; ++rr)
        atomicAdd(&S[(size_t)bi * 128 + ibase + rr], rs[rr]);
    }
  }
  if (bi != bj) {   // mirror: (j,i) identical by symmetry -> column sums
    #pragma unroll
    for (int tj = 0; tj < 2; ++tj) {
      cs[tj] += __shfl_xor(cs[tj], 16);   // reduce over lr
      cs[tj] += __shfl_xor(cs[tj], 32);
    }
    if (lr == 0) {
      #pragma unroll
      for (int tj = 0; tj < 2; ++tj)
        atomicAdd(&S[(size_t)bj * 128 + wj * 32 + tj * 16 + lc], cs[tj]);
    }
  }
}

// ---------------- KF: final reduction — fp32 out -----------------------------
__global__ __launch_bounds__(1024) void kf_final_v9(const float* __restrict__ possim,
                                                    const float* __restrict__ scsim,
                                                    const float* __restrict__ S,
                                                    const int* __restrict__ counters,
                                                    float* __restrict__ out) {
  __shared__ float red[1024];
  int tid = threadIdx.x;
  int nconf = counters[3];
  float local = 0.f;
  for (int i = tid; i < N_ROWS; i += 1024) {
    float p = (i < nconf) ? possim[i] : scsim[i];
    p = fminf(fmaxf(p, -1.1f), 1.1f);      // |pos|<=1 math bound (safety)
    float s = fmaxf(S[i], 0.0f);
    local += logf(expf(p) + s) - p;        // -logp[:,0]
  }
  red[tid] = local;
  __syncthreads();
  for (int s = 512; s > 0; s >>= 1) {
    if (tid < s) red[tid] += red[tid + s];
    __syncthreads();
  }
  if (tid == 0) {
    float loss = red[0] / (float)N_ROWS;
    int scc = counters[0], dn = counters[1];
    float scn = (dn > 0) ? ((float)scc / (float)(dn > 1 ? dn : 1)) : 0.f;
    out[0] = loss;
    out[1] = scn;
  }
}

extern "C" void kernel_launch(void* const* d_in, const int* in_sizes, int n_in,
                              void* d_out, int out_size, void* d_ws, size_t ws_size,
                              hipStream_t stream) {
  const float* feature   = (const float*)d_in[0];
  const float* proxy_raw = (const float*)d_in[1];
  const float* cP        = (const float*)d_in[2];
  const float* prob      = (const float*)d_in[3];
  const int*   conf      = (const int*)d_in[4];
  float* out = (float*)d_out;

  size_t need = (size_t)N_ROWS * DIM * 2      // featBF    8 MB
              + (size_t)N_ROWS * DIM          // featF8    4 MB
              + (size_t)C_PAD * DIM * 2       // proxyBF   1 MB
              + (size_t)N_ROWS * 16 * 8       // bits      1 MB
              + (size_t)N_ROWS * 4            // possim
              + (size_t)N_ROWS * 4            // S
              + (size_t)N_ROWS * 4            // scsim
              + 256                           // counters
              + (size_t)N_ROWS * 4            // perm
              + (size_t)N_ROWS * 4;           // top1a
  if (ws_size < need) return;

  char* ws = (char*)d_ws;
  __bf16* featBF  = (__bf16*)ws;         ws += (size_t)N_ROWS * DIM * 2;
  unsigned char* featF8 = (unsigned char*)ws; ws += (size_t)N_ROWS * DIM;
  __bf16* proxyBF = (__bf16*)ws;         ws += (size_t)C_PAD * DIM * 2;
  ull* bits       = (ull*)ws;            ws += (size_t)N_ROWS * 16 * 8;
  float* possim   = (float*)ws;          ws += (size_t)N_ROWS * 4;
  float* S        = (float*)ws;          ws += (size_t)N_ROWS * 4;   // S, scsim, counters contiguous
  float* scsim    = (float*)ws;          ws += (size_t)N_ROWS * 4;
  int* counters   = (int*)ws;            ws += 256;  // [0]=sc_count [1]=denom [3]=nconf
  int* perm       = (int*)ws;            ws += (size_t)N_ROWS * 4;
  int* top1a      = (int*)ws;            ws += (size_t)N_ROWS * 4;

  hipMemsetAsync(S, 0, (size_t)N_ROWS * 8 + 256, stream);  // zero S + scsim + counters
  kzp_v9<<<1, 1024, 0, stream>>>(conf, perm, counters);
  kda_v9<<<N_ROWS / 4, 256, 0, stream>>>(prob, feature, perm, bits, top1a, featBF, featF8, counters);
  kbc_v9<<<C_PAD / 8, 256, 0, stream>>>(proxy_raw, cP, proxyBF);
  kg_pgemm_v9<<<64 * 8, 512, 0, stream>>>(featBF, proxyBF, prob, perm, top1a, scsim, possim);
  ke_sim_v9<<<2080, 512, 0, stream>>>(featF8, bits, top1a, counters, S);
  kf_final_v9<<<1, 1024, 0, stream>>>(possim, scsim, S, counters, out);
}